// Round 3
// baseline (130.325 us; speedup 1.0000x reference)
//
#include <hip/hip_runtime.h>
#include <math.h>

#define N_NODES 4096
#define F_IN    512
#define F_OUT   64
#define ALPHA   0.2f

typedef _Float16 half8 __attribute__((ext_vector_type(8)));
typedef _Float16 half4 __attribute__((ext_vector_type(4)));
typedef float    floatx4 __attribute__((ext_vector_type(4)));

union H8U4 { half8 h; uint32_t u[4]; };

// async global->LDS DMA, 16B per lane, dest = lds_base + lane*16 (wave-uniform base)
__device__ __forceinline__ void async_copy16(void* lds, const void* g) {
    __builtin_amdgcn_global_load_lds(
        (const __attribute__((address_space(1))) unsigned int*)g,
        (__attribute__((address_space(3))) unsigned int*)lds, 16, 0, 0);
}

// ---------------- k_hW: h = x@W via MFMA, K-split across 8 waves, W gathered on the fly ----------------
// grid 256 x 512: block = 16 rows; wave w (0..7) covers K slice [w*64, w*64+64).
// k_prep eliminated: bf[j] = (f16)W[k][t] gathered directly (W is 128KB, L2-resident) —
// bit-identical values to the old WT path.
__global__ __launch_bounds__(512) void k_hW(const float* __restrict__ x,
                                            const float* __restrict__ W,
                                            const float* __restrict__ a,
                                            float* __restrict__ h,
                                            _Float16* __restrict__ hT,
                                            float* __restrict__ e1) {
    __shared__ float red[8][16][64];   // [wave][g4*4+r][lane]  32 KB
    int tid  = threadIdx.x;
    int lane = tid & 63;
    int w    = tid >> 6;               // 0..7
    int i0   = blockIdx.x * 16;
    int n    = lane & 15;
    int quad = lane >> 4;

    floatx4 acc[4] = {{0,0,0,0},{0,0,0,0},{0,0,0,0},{0,0,0,0}};

    const float* xr = x + (size_t)(i0 + n) * F_IN + w * 64 + quad * 8;
#pragma unroll
    for (int kk = 0; kk < 64; kk += 32) {
        float4 x0 = *(const float4*)(xr + kk);
        float4 x1 = *(const float4*)(xr + kk + 4);
        half8 af = {(_Float16)x0.x, (_Float16)x0.y, (_Float16)x0.z, (_Float16)x0.w,
                    (_Float16)x1.x, (_Float16)x1.y, (_Float16)x1.z, (_Float16)x1.w};
        int k0 = w * 64 + kk + quad * 8;
#pragma unroll
        for (int g = 0; g < 4; ++g) {
            const float* wc = W + (size_t)k0 * F_OUT + g * 16 + n;   // column t = g*16+n
            half8 bf = {(_Float16)wc[0 * 64], (_Float16)wc[1 * 64], (_Float16)wc[2 * 64], (_Float16)wc[3 * 64],
                        (_Float16)wc[4 * 64], (_Float16)wc[5 * 64], (_Float16)wc[6 * 64], (_Float16)wc[7 * 64]};
            acc[g] = __builtin_amdgcn_mfma_f32_16x16x32_f16(af, bf, acc[g], 0, 0, 0);
        }
    }
#pragma unroll
    for (int g = 0; g < 4; ++g)
#pragma unroll
        for (int r = 0; r < 4; ++r)
            red[w][g * 4 + r][lane] = acc[g][r];
    __syncthreads();
    if (w != 0) return;
#pragma unroll
    for (int g = 0; g < 4; ++g)
#pragma unroll
        for (int r = 0; r < 4; ++r) {
            float v = 0.f;
#pragma unroll
            for (int ww = 0; ww < 8; ++ww)
                v += red[ww][g * 4 + r][lane];
            acc[g][r] = v;
        }
#pragma unroll
    for (int g = 0; g < 4; ++g) {
        half4 hv;
#pragma unroll
        for (int r = 0; r < 4; ++r) {
            h[(size_t)(i0 + quad * 4 + r) * F_OUT + g * 16 + n] = acc[g][r];
            hv[r] = (_Float16)acc[g][r];
        }
        *(half4*)(hT + (size_t)(g * 16 + n) * N_NODES + i0 + quad * 4) = hv;
    }
    float a1v[4];
#pragma unroll
    for (int g = 0; g < 4; ++g) a1v[g] = a[g * 16 + n];
#pragma unroll
    for (int r = 0; r < 4; ++r) {
        float v = acc[0][r] * a1v[0] + acc[1][r] * a1v[1] + acc[2][r] * a1v[2] + acc[3][r] * a1v[3];
        v += __shfl_xor(v, 1, 64);
        v += __shfl_xor(v, 2, 64);
        v += __shfl_xor(v, 4, 64);
        v += __shfl_xor(v, 8, 64);
        if (n == 0) e1[i0 + quad * 4 + r] = v;
    }
}

// ---------------- k_main2: row-complete attention blocks; wave-autonomous DMA pipeline ----------------
// grid 256 x 512: block b owns output rows [b*16, b*16+16) x ALL 4096 columns.
// Wave w streams column strip [w*512, w*512+512) in 16 stages of 32 cols, double-buffered,
// counted vmcnt(6), NO barrier in the main loop (each wave reads only its own LDS regions).
// Softmax denominator completes in-block -> relu+bias+store out directly (k_out + out_part deleted).
union ShM {
    struct {                           // streaming phase
        int      adjS[8][2][2][256];   // [w][buf][c][lane*4 ints]   32 KB
        _Float16 BS[8][2][4][512];     // [w][buf][tb][lane*8 halfs] 64 KB
    } st;
    struct {                           // reduction phase: red[w] aliases adjS[w] (own region only)
        float red[8][16][64];          // 32 KB
    } rd;
};

__global__ __launch_bounds__(512, 2) void k_main2(const int* __restrict__ adj,
                                                  const float* __restrict__ h,
                                                  const float* __restrict__ e1,
                                                  const float* __restrict__ a,
                                                  const _Float16* __restrict__ hT,
                                                  const float* __restrict__ bias,
                                                  float* __restrict__ out) {
    __shared__ ShM shm;                // 96 KB
    __shared__ _Float16 P[4096];       //  8 KB
    __shared__ float part[8][64];      //  2 KB (prologue scratch; reused for denominators)
    __shared__ float Tq[64];

    int tid  = threadIdx.x;
    int lane = tid & 63;
    int w    = tid >> 6;               // 0..7 = column strip owner
    int b    = blockIdx.x;
    int i0   = b * 16;                 // first output row
    int rbq  = b >> 2;                 // 64-row group for Tq (rows i0..i0+15 all lie in it)
    int n    = lane & 15;
    int quad = lane >> 4;

    // per-stage DMA: 2 adj copies (16 rows x 32 cols) + 4 hT copies (64 t x 32 cols)
#define STG(t_) do {                                                                \
        const int bf_ = (t_) & 1;                                                   \
        const int j0_ = w * 512 + (t_) * 32;                                        \
        const int* ab_ = adj + (size_t)(i0 + n) * N_NODES + j0_ + quad * 4;         \
        async_copy16(&shm.st.adjS[w][bf_][0][0], ab_);                              \
        async_copy16(&shm.st.adjS[w][bf_][1][0], ab_ + 16);                         \
        const _Float16* hb_ = hT + (size_t)n * N_NODES + j0_ + quad * 8;            \
        async_copy16(&shm.st.BS[w][bf_][0][0], hb_);                                \
        async_copy16(&shm.st.BS[w][bf_][1][0], hb_ + 16 * N_NODES);                 \
        async_copy16(&shm.st.BS[w][bf_][2][0], hb_ + 32 * N_NODES);                 \
        async_copy16(&shm.st.BS[w][bf_][3][0], hb_ + 48 * N_NODES);                 \
    } while (0)

    STG(0);   // HBM latency hides under the Tq/P prologue

    // ---- Tq[t] = sum_r a2[r] * h[(r*64+rbq)*64 + t] ----
    {
        int t  = tid & 63;
        int rp = tid >> 6;
        const float* a2 = a + F_OUT;
        float ss = 0.f;
#pragma unroll
        for (int rr = 0; rr < 8; ++rr) {
            int r = rp * 8 + rr;
            ss += a2[r] * h[(size_t)r * 4096 + rbq * 64 + t];
        }
        part[rp][t] = ss;
    }
    __syncthreads();
    if (tid < 64)
        Tq[tid] = part[0][tid] + part[1][tid] + part[2][tid] + part[3][tid]
                + part[4][tid] + part[5][tid] + part[6][tid] + part[7][tid];
    __syncthreads();
    // ---- P[j] = exp(leaky(e1[j] + Tq[j&63])) for the full 4096-col row (8 per thread) ----
    {
        int j8 = tid * 8;
        float4 ev0 = *(const float4*)(e1 + j8);
        float4 ev1 = *(const float4*)(e1 + j8 + 4);
        float ev[8] = {ev0.x, ev0.y, ev0.z, ev0.w, ev1.x, ev1.y, ev1.z, ev1.w};
        half8 ph;
#pragma unroll
        for (int u = 0; u < 8; ++u) {
            float val = ev[u] + Tq[(j8 + u) & 63];
            val = val > 0.f ? val : ALPHA * val;
            ph[u] = (_Float16)__expf(val);
        }
        *(half8*)&P[j8] = ph;
    }
    __syncthreads();   // P visible to all waves; also drains STG(0)

    floatx4 acc[4] = {{0,0,0,0},{0,0,0,0},{0,0,0,0},{0,0,0,0}};
    floatx4 accd = {0, 0, 0, 0};
    _Float16 one_h = (n == 0) ? (_Float16)1.0f : (_Float16)0.0f;
    half8 ones_f = {one_h, one_h, one_h, one_h, one_h, one_h, one_h, one_h};

    const int ia = (((2 * quad) & 3) * 16 + n) * 4;       // int4 slot of adj cols quad*8..+3
    const int ib = (((2 * quad + 1) & 3) * 16 + n) * 4;   // int4 slot of adj cols quad*8+4..+7
    const int cq = quad >> 1;

#pragma unroll 2
    for (int st = 0; st < 16; ++st) {
        if (st < 15) {
            STG(st + 1);                                   // prefetch into alternate buffer
            asm volatile("s_waitcnt vmcnt(6)" ::: "memory");  // own current stage landed
        } else {
            asm volatile("s_waitcnt vmcnt(0)" ::: "memory");
        }
        __builtin_amdgcn_sched_barrier(0);                 // keep LDS reads below the wait

        const int buf = st & 1;
        const int j0  = w * 512 + st * 32;
        int4 ga = *(const int4*)&shm.st.adjS[w][buf][cq][ia];
        int4 gb = *(const int4*)&shm.st.adjS[w][buf][cq][ib];
        H8U4 pv, af;
        pv.h = *(const half8*)&P[j0 + quad * 8];
        af.u[0] = pv.u[0] & ((ga.x > 0 ? 0x0000FFFFu : 0u) | (ga.y > 0 ? 0xFFFF0000u : 0u));
        af.u[1] = pv.u[1] & ((ga.z > 0 ? 0x0000FFFFu : 0u) | (ga.w > 0 ? 0xFFFF0000u : 0u));
        af.u[2] = pv.u[2] & ((gb.x > 0 ? 0x0000FFFFu : 0u) | (gb.y > 0 ? 0xFFFF0000u : 0u));
        af.u[3] = pv.u[3] & ((gb.z > 0 ? 0x0000FFFFu : 0u) | (gb.w > 0 ? 0xFFFF0000u : 0u));
#pragma unroll
        for (int g4 = 0; g4 < 4; ++g4) {
            half8 bf = *(const half8*)&shm.st.BS[w][buf][g4][lane * 8];
            acc[g4] = __builtin_amdgcn_mfma_f32_16x16x32_f16(af.h, bf, acc[g4], 0, 0, 0);
        }
        accd = __builtin_amdgcn_mfma_f32_16x16x32_f16(af.h, ones_f, accd, 0, 0, 0);
    }
#undef STG

    // ---- per-wave partials -> LDS. red[w] aliases adjS[w] (this wave's OWN region, loop done).
    // Denominators go to `part` (dead since prologue) to avoid aliasing other waves' BS.
#pragma unroll
    for (int g4 = 0; g4 < 4; ++g4)
#pragma unroll
        for (int r = 0; r < 4; ++r)
            shm.rd.red[w][quad * 4 + r][g4 * 16 + n] = acc[g4][r];
    if (n == 0) {
#pragma unroll
        for (int r = 0; r < 4; ++r)
            part[w][quad * 4 + r] = accd[r];
    }
    __syncthreads();

    // ---- reduce 8 waves, relu+bias, store out (16 rows x 64 cols) ----
#pragma unroll
    for (int e = tid; e < 1024; e += 512) {
        int row = e >> 6;
        int t   = e & 63;
        float num = 0.f, den = 0.f;
#pragma unroll
        for (int ww = 0; ww < 8; ++ww) {
            num += shm.rd.red[ww][row][t];
            den += part[ww][row];
        }
        out[(size_t)(i0 + row) * F_OUT + t] = fmaxf(num / den, 0.f) + bias[t];
    }
}

extern "C" void kernel_launch(void* const* d_in, const int* in_sizes, int n_in,
                              void* d_out, int out_size, void* d_ws, size_t ws_size,
                              hipStream_t stream) {
    const float* x    = (const float*)d_in[0];
    const int*   adj  = (const int*)d_in[1];
    const float* W    = (const float*)d_in[2];
    const float* a    = (const float*)d_in[3];
    const float* bias = (const float*)d_in[4];
    float* out = (float*)d_out;

    char* ws = (char*)d_ws;
    float*    h  = (float*)ws;                      // 1 MB
    _Float16* hT = (_Float16*)(ws + 1024 * 1024);   // 512 KB
    float*    e1 = (float*)(ws + 1536 * 1024);      // 16 KB

    k_hW   <<<256, 512, 0, stream>>>(x, W, a, h, hT, e1);
    k_main2<<<256, 512, 0, stream>>>(adj, h, e1, a, hT, bias, out);
}

// Round 4
// 123.476 us; speedup vs baseline: 1.0555x; 1.0555x over previous
//
#include <hip/hip_runtime.h>
#include <math.h>

#define N_NODES 4096
#define F_IN    512
#define F_OUT   64
#define ALPHA   0.2f
#define NPART   16

typedef _Float16 half8 __attribute__((ext_vector_type(8)));
typedef _Float16 half4 __attribute__((ext_vector_type(4)));
typedef float    floatx4 __attribute__((ext_vector_type(4)));

union H8U4 { half8 h; uint32_t u[4]; };

// async global->LDS DMA, 16B per lane, dest = lds_base + lane*16 (wave-uniform base),
// global source address is PER-LANE.
__device__ __forceinline__ void async_copy16(void* lds, const void* g) {
    __builtin_amdgcn_global_load_lds(
        (const __attribute__((address_space(1))) unsigned int*)g,
        (__attribute__((address_space(3))) unsigned int*)lds, 16, 0, 0);
}

// ---------------- k_prep: WT[t][k] = f16(W[k][t])  (64 x 512) ----------------
__global__ __launch_bounds__(256) void k_prep(const float* __restrict__ W,
                                              _Float16* __restrict__ WT) {
    int idx = blockIdx.x * 256 + threadIdx.x;   // 32768 total
    int t = idx >> 9;
    int k = idx & 511;
    WT[idx] = (_Float16)W[k * F_OUT + t];
}

// ---------------- k_hW: h = x@W via MFMA, K-split across 8 waves (512-thr blocks) ----------------
__global__ __launch_bounds__(512) void k_hW(const float* __restrict__ x,
                                            const _Float16* __restrict__ WT,
                                            const float* __restrict__ a,
                                            float* __restrict__ h,
                                            _Float16* __restrict__ hT,
                                            float* __restrict__ e1) {
    __shared__ float red[8][16][64];   // [wave][g4*4+r][lane]  32 KB
    int tid  = threadIdx.x;
    int lane = tid & 63;
    int w    = tid >> 6;               // 0..7
    int i0   = blockIdx.x * 16;
    int n    = lane & 15;
    int quad = lane >> 4;

    floatx4 acc[4] = {{0,0,0,0},{0,0,0,0},{0,0,0,0},{0,0,0,0}};

    const float* xr = x + (size_t)(i0 + n) * F_IN + w * 64 + quad * 8;
    const _Float16* wb = WT + w * 64 + quad * 8;
#pragma unroll
    for (int kk = 0; kk < 64; kk += 32) {
        float4 x0 = *(const float4*)(xr + kk);
        float4 x1 = *(const float4*)(xr + kk + 4);
        half8 af = {(_Float16)x0.x, (_Float16)x0.y, (_Float16)x0.z, (_Float16)x0.w,
                    (_Float16)x1.x, (_Float16)x1.y, (_Float16)x1.z, (_Float16)x1.w};
#pragma unroll
        for (int g = 0; g < 4; ++g) {
            half8 bf = *(const half8*)(wb + (size_t)(g * 16 + n) * F_IN + kk);
            acc[g] = __builtin_amdgcn_mfma_f32_16x16x32_f16(af, bf, acc[g], 0, 0, 0);
        }
    }
#pragma unroll
    for (int g = 0; g < 4; ++g)
#pragma unroll
        for (int r = 0; r < 4; ++r)
            red[w][g * 4 + r][lane] = acc[g][r];
    __syncthreads();
    if (w != 0) return;
#pragma unroll
    for (int g = 0; g < 4; ++g)
#pragma unroll
        for (int r = 0; r < 4; ++r) {
            float v = 0.f;
#pragma unroll
            for (int ww = 0; ww < 8; ++ww)
                v += red[ww][g * 4 + r][lane];
            acc[g][r] = v;
        }
#pragma unroll
    for (int g = 0; g < 4; ++g) {
        half4 hv;
#pragma unroll
        for (int r = 0; r < 4; ++r) {
            h[(size_t)(i0 + quad * 4 + r) * F_OUT + g * 16 + n] = acc[g][r];
            hv[r] = (_Float16)acc[g][r];
        }
        *(half4*)(hT + (size_t)(g * 16 + n) * N_NODES + i0 + quad * 4) = hv;
    }
    float a1v[4];
#pragma unroll
    for (int g = 0; g < 4; ++g) a1v[g] = a[g * 16 + n];
#pragma unroll
    for (int r = 0; r < 4; ++r) {
        float v = acc[0][r] * a1v[0] + acc[1][r] * a1v[1] + acc[2][r] * a1v[2] + acc[3][r] * a1v[3];
        v += __shfl_xor(v, 1, 64);
        v += __shfl_xor(v, 2, 64);
        v += __shfl_xor(v, 4, 64);
        v += __shfl_xor(v, 8, 64);
        if (n == 0) e1[i0 + quad * 4 + r] = v;
    }
}

// ---------------- k_main: HIGH-OCCUPANCY masked MFMA pipeline ----------------
// grid 1024: b -> rb = b>>4 (64-row block), s = b&15 (256-col superchunk = 8 x 32-col stages).
// LDS 25.75 KB -> 4 blocks/CU (launch_bounds(256,4)) = 16 waves/CU: the occupancy A/B vs
// round 0/1's 2 blocks/CU. Double-buffered stages, counted vmcnt(3), two raw barriers/stage.
__global__ __launch_bounds__(256, 4) void k_main(const int* __restrict__ adj,
                                                 const float* __restrict__ h,
                                                 const float* __restrict__ e1,
                                                 const float* __restrict__ a,
                                                 const _Float16* __restrict__ hT,
                                                 float* __restrict__ out_part,
                                                 float* __restrict__ den_part) {
    __shared__ int      lds_adj[4][2][2][256];  // [wave][buf][c][ (quad*16+n)*4 ]  16 KB
    __shared__ _Float16 lds_B[4][2][16][32];    // [g4][buf][t-local][col]           8 KB
    __shared__ _Float16 lds_P[256];             //  0.5 KB
    __shared__ float    lds_part[4][64];        //  1 KB
    __shared__ float    TqS[64];                //  0.25 KB

    int tid  = threadIdx.x;
    int lane = tid & 63;
    int w    = tid >> 6;               // 0..3
    int b    = blockIdx.x;
    int rb   = b >> 4;                 // 64-row group (0..63)
    int s    = b & 15;                 // 256-col superchunk (0..15)
    int i0   = rb * 64 + w * 16;
    int n    = lane & 15;
    int quad = lane >> 4;

    // per-stage DMA: 2 adj copies (16 rows x 32 cols, this wave's rows)
    //              + 1 hT copy (wave's 16 t-rows x 32 cols). 3 DMAs/wave/stage.
    // B src mapping: lane l -> t = w*16 + (l>>2), col = (l&3)*8 so linear LDS dest
    // [l>>2][(l&3)*8] is row-major [16][32].
#define STG(t_) do {                                                                    \
        const int bf_ = (t_) & 1;                                                       \
        const int jb_ = s * 256 + (t_) * 32;                                            \
        const int* ab_ = adj + (size_t)(i0 + n) * N_NODES + jb_ + quad * 8;             \
        async_copy16(&lds_adj[w][bf_][0][0], ab_);                                      \
        async_copy16(&lds_adj[w][bf_][1][0], ab_ + 4);                                  \
        const _Float16* hb_ = hT + (size_t)(w * 16 + (lane >> 2)) * N_NODES             \
                                 + jb_ + (lane & 3) * 8;                                \
        async_copy16(&lds_B[w][bf_][0][0], hb_);                                        \
    } while (0)

    STG(0);   // HBM latency hides under the Tq/P prologue

    // ---- Tq[t] = sum_{r=0}^{63} a2[r] * h[(r*64+rb)*64 + t] ----
    {
        int t  = tid & 63;
        int rp = tid >> 6;
        const float* a2 = a + F_OUT;
        float ssum = 0.f;
#pragma unroll
        for (int rr = 0; rr < 16; ++rr) {
            int r = rp * 16 + rr;
            ssum += a2[r] * h[(size_t)r * 4096 + rb * 64 + t];
        }
        lds_part[rp][t] = ssum;
    }
    __syncthreads();
    if (tid < 64)
        TqS[tid] = lds_part[0][tid] + lds_part[1][tid] + lds_part[2][tid] + lds_part[3][tid];
    __syncthreads();
    // ---- P strip for this block's 256 cols: 1 expf per thread ----
    {
        int j = s * 256 + tid;
        float e0 = e1[j] + TqS[tid & 63];
        e0 = e0 > 0.f ? e0 : ALPHA * e0;
        lds_P[tid] = (_Float16)__expf(e0);
    }
    __syncthreads();   // P visible to all waves (drains lgkm before barrier)

    floatx4 acc[4] = {{0,0,0,0},{0,0,0,0},{0,0,0,0},{0,0,0,0}};
    floatx4 accd = {0, 0, 0, 0};
    _Float16 one_h = (n == 0) ? (_Float16)1.0f : (_Float16)0.0f;
    half8 ones_f = {one_h, one_h, one_h, one_h, one_h, one_h, one_h, one_h};

#pragma unroll
    for (int st = 0; st < 8; ++st) {
        if (st < 7) {
            STG(st + 1);                                      // prefetch alternate buffer
            asm volatile("s_waitcnt vmcnt(3)" ::: "memory");  // own stage-st DMAs landed
        } else {
            asm volatile("s_waitcnt vmcnt(0)" ::: "memory");
        }
        __builtin_amdgcn_s_barrier();        // all waves' stage-st data in LDS
        __builtin_amdgcn_sched_barrier(0);   // keep LDS reads below wait+barrier

        const int buf = st & 1;
        // adj cols quad*8+{0..3} and {4..7} of row n:
        int4 ga = *(const int4*)&lds_adj[w][buf][0][(quad * 16 + n) * 4];
        int4 gb = *(const int4*)&lds_adj[w][buf][1][(quad * 16 + n) * 4];
        H8U4 pv, af;
        pv.h = *(const half8*)&lds_P[st * 32 + quad * 8];
        af.u[0] = pv.u[0] & ((ga.x > 0 ? 0x0000FFFFu : 0u) | (ga.y > 0 ? 0xFFFF0000u : 0u));
        af.u[1] = pv.u[1] & ((ga.z > 0 ? 0x0000FFFFu : 0u) | (ga.w > 0 ? 0xFFFF0000u : 0u));
        af.u[2] = pv.u[2] & ((gb.x > 0 ? 0x0000FFFFu : 0u) | (gb.y > 0 ? 0xFFFF0000u : 0u));
        af.u[3] = pv.u[3] & ((gb.z > 0 ? 0x0000FFFFu : 0u) | (gb.w > 0 ? 0xFFFF0000u : 0u));
#pragma unroll
        for (int g4 = 0; g4 < 4; ++g4) {
            // B-fragment: lane (n,quad) needs hT[g4*16+n][stage cols quad*8..+8]
            half8 bf = *(const half8*)&lds_B[g4][buf][n][quad * 8];
            acc[g4] = __builtin_amdgcn_mfma_f32_16x16x32_f16(af.h, bf, acc[g4], 0, 0, 0);
        }
        accd = __builtin_amdgcn_mfma_f32_16x16x32_f16(af.h, ones_f, accd, 0, 0, 0);

        __builtin_amdgcn_sched_barrier(0);
        __builtin_amdgcn_s_barrier();        // all waves done reading buf before re-stage
    }
#undef STG

    // ---- store this superchunk's private partial (C: row = quad*4+r, col = g4*16+n) ----
    float* op = out_part + ((size_t)s * N_NODES + i0) * F_OUT;
#pragma unroll
    for (int g4 = 0; g4 < 4; ++g4)
#pragma unroll
        for (int r = 0; r < 4; ++r)
            op[(quad * 4 + r) * F_OUT + g4 * 16 + n] = acc[g4][r];
    if (n == 0) {
#pragma unroll
        for (int r = 0; r < 4; ++r)
            den_part[s * N_NODES + i0 + quad * 4 + r] = accd[r];
    }
}

// ---------------- k_out: out = relu(sum_s out_part / sum_s den_part) + bias (float4) ----------------
__global__ __launch_bounds__(128) void k_out(const float* __restrict__ out_part,
                                             const float* __restrict__ den_part,
                                             const float* __restrict__ bias,
                                             float* __restrict__ out) {
    int idx4 = blockIdx.x * 128 + threadIdx.x;   // 65536 float4s
    int base = idx4 * 4;
    int i = base >> 6;
    int t = base & 63;
    float4 sacc = {0.f, 0.f, 0.f, 0.f};
    float dacc = 0.f;
#pragma unroll
    for (int p = 0; p < NPART; ++p) {
        float4 v = ((const float4*)(out_part + (size_t)p * N_NODES * F_OUT))[idx4];
        sacc.x += v.x; sacc.y += v.y; sacc.z += v.z; sacc.w += v.w;
        dacc += den_part[p * N_NODES + i];
    }
    float4 bv = *(const float4*)(bias + t);
    float4 o;
    o.x = fmaxf(sacc.x / dacc, 0.f) + bv.x;
    o.y = fmaxf(sacc.y / dacc, 0.f) + bv.y;
    o.z = fmaxf(sacc.z / dacc, 0.f) + bv.z;
    o.w = fmaxf(sacc.w / dacc, 0.f) + bv.w;
    ((float4*)out)[idx4] = o;
}

extern "C" void kernel_launch(void* const* d_in, const int* in_sizes, int n_in,
                              void* d_out, int out_size, void* d_ws, size_t ws_size,
                              hipStream_t stream) {
    const float* x    = (const float*)d_in[0];
    const int*   adj  = (const int*)d_in[1];
    const float* W    = (const float*)d_in[2];
    const float* a    = (const float*)d_in[3];
    const float* bias = (const float*)d_in[4];
    float* out = (float*)d_out;

    char* ws = (char*)d_ws;
    float*    h        = (float*)ws;                             // 1 MB
    _Float16* hT       = (_Float16*)(ws + 1024 * 1024);          // 512 KB
    float*    e1       = (float*)(ws + 1536 * 1024);             // 16 KB
    _Float16* WT       = (_Float16*)(ws + 1552 * 1024);          // 64 KB
    float*    out_part = (float*)(ws + 2128 * 1024);             // 16 MB (NPART=16, fp32)
    float*    den_part = (float*)(ws + (2128 + 16384) * 1024);   // 256 KB

    k_prep<<<128, 256, 0, stream>>>(W, WT);
    k_hW  <<<256, 512, 0, stream>>>(x, WT, a, h, hT, e1);
    k_main<<<1024, 256, 0, stream>>>(adj, h, e1, a, hT, out_part, den_part);
    k_out <<<512, 128, 0, stream>>>(out_part, den_part, bias, out);
}